// Round 10
// baseline (68.990 us; speedup 1.0000x reference)
//
#include <hip/hip_runtime.h>
#include <math.h>

#define BB 256
#define NN 1024
#define DD 128
#define NCHUNK 4
#define ROWS (NN / NCHUNK)   // 256

// workspace layout (in floats)
#define PA_OFF   0
#define PCI_OFF  (NCHUNK*BB*DD)            // 131072
#define PCJ_OFF  (2*NCHUNK*BB*DD)          // 262144
#define PCNT_OFF (3*NCHUNK*BB*DD)          // 393216
#define U_OFF    (PCNT_OFF + NCHUNK*BB)    // 394240
#define V_OFF    (U_OFF + BB*DD)           // 427008
// total = 459776 floats = 1.84 MB

// ---------------------------------------------------------------------------
// Kernel 1: SPARSE masked streaming reductions over N, one array per block.
//   role 0: P_A[chunk][b][k]  = sum_n (mi-mj) * d[b,n,k]   (+ cnt via popc)
//   role 1: P_Ci[chunk][b][k] = sum_n  mi     * si[b,n,k]
//   role 2: P_Cj[chunk][b][k] = sum_n  mj     * sj[b,n,k]
// Rows with zero weight (~50%) are compacted away in LDS and NEVER LOADED.
// grid = (NCHUNK, BB, 3), block = 256 (32 lanes x 8 row-groups).
// (unchanged from round 9 — isolates this round's k2 experiment)
// ---------------------------------------------------------------------------
__global__ __launch_bounds__(256) void k1_sparse(
    const float* __restrict__ d, const float* __restrict__ si,
    const float* __restrict__ sj, const void* __restrict__ miv,
    const void* __restrict__ mjv, float* __restrict__ ws)
{
    const int chunk = blockIdx.x;
    const int b     = blockIdx.y;
    const int role  = blockIdx.z;
    const int t     = threadIdx.x;
    const int lane  = t & 31;   // float4 column group: cols lane*4 .. +3
    const int rg    = t >> 5;   // row group 0..7
    const int wid   = t >> 6;   // wave 0..3
    const int l64   = t & 63;

    // ---- mask dtype auto-detect (bool bytes vs int32) ----
    __shared__ int s_mode;
    if (t == 0) s_mode = 0;
    __syncthreads();
    {
        const unsigned int* a = (const unsigned int*)miv;
        const unsigned int* c = (const unsigned int*)mjv;
        if ((a[t] | c[t]) > 1u) s_mode = 1;  // bytes of 0/1 packed in a word
    }
    __syncthreads();
    const bool bytes_mode = (s_mode != 0);

    // ---- stage weights, compute cnt (role 0), compact nonzero rows ----
    __shared__ float s_wc[ROWS];     // compacted weights
    __shared__ short s_idx[ROWS];    // compacted row indices (0..255)
    __shared__ int   s_wcnt[4];      // per-wave keep counts
    __shared__ int   s_woff[5];      // exclusive scan + total
    __shared__ int   s_cnt4[4];      // per-wave (sum mi - sum mj)

    const int    n0      = chunk * ROWS;
    const size_t rowbase = (size_t)b * NN;

    float w;
    {
        const size_t m = rowbase + (size_t)(n0 + t);
        float fi, fj;
        if (bytes_mode) {
            fi = (float)((const unsigned char*)miv)[m];
            fj = (float)((const unsigned char*)mjv)[m];
        } else {
            fi = (float)((const int*)miv)[m];
            fj = (float)((const int*)mjv)[m];
        }
        w = (role == 0) ? (fi - fj) : ((role == 1) ? fi : fj);
        if (role == 0) {
            const unsigned long long bi = __ballot(fi != 0.f);
            const unsigned long long bj = __ballot(fj != 0.f);
            if (l64 == 0) s_cnt4[wid] = __popcll(bi) - __popcll(bj);
        }
    }
    const bool keep = (w != 0.f);
    const unsigned long long ball = __ballot(keep);
    const int prefix = __popcll(ball & ((1ull << l64) - 1ull));
    if (l64 == 0) s_wcnt[wid] = __popcll(ball);
    __syncthreads();
    if (t == 0) {
        int a0 = 0;
        #pragma unroll
        for (int ww = 0; ww < 4; ++ww) { s_woff[ww] = a0; a0 += s_wcnt[ww]; }
        s_woff[4] = a0;
        if (role == 0)
            ws[PCNT_OFF + chunk * BB + b] =
                (float)(s_cnt4[0] + s_cnt4[1] + s_cnt4[2] + s_cnt4[3]);
    }
    __syncthreads();
    const int K    = s_woff[4];
    const int Kpad = (K + 31) & ~31;
    if (keep) {
        const int pos = s_woff[wid] + prefix;
        s_idx[pos] = (short)t;
        s_wc[pos]  = w;
    }
    for (int p = K + t; p < Kpad; p += 256) { s_idx[p] = 0; s_wc[p] = 0.f; }
    __syncthreads();

    const float* src = (role == 0) ? d : ((role == 1) ? si : sj);
    const size_t cbase = (rowbase + (size_t)n0) * (size_t)DD
                       + (size_t)lane * 4;

    float acc[4] = {0.f, 0.f, 0.f, 0.f};

    for (int i = 0; i < Kpad; i += 32) {
        int   r[4];
        float wv[4];
        #pragma unroll
        for (int u = 0; u < 4; ++u) {
            const int p = i + u * 8 + rg;
            r[u]  = s_idx[p];      // broadcast within row-group
            wv[u] = s_wc[p];
        }
        float4 v[4];
        #pragma unroll
        for (int u = 0; u < 4; ++u)
            v[u] = *(const float4*)(src + cbase + (size_t)r[u] * DD);
        #pragma unroll
        for (int u = 0; u < 4; ++u) {
            acc[0] = fmaf(wv[u], v[u].x, acc[0]);
            acc[1] = fmaf(wv[u], v[u].y, acc[1]);
            acc[2] = fmaf(wv[u], v[u].z, acc[2]);
            acc[3] = fmaf(wv[u], v[u].w, acc[3]);
        }
    }

    // ---- reduce the 8 row-groups (t strides of 32); [5] breaks bank stride
    __shared__ float red[256][5];
    #pragma unroll
    for (int i = 0; i < 4; ++i) red[t][i] = acc[i];
    __syncthreads();
    if (t < 128) {
        #pragma unroll
        for (int i = 0; i < 4; ++i) red[t][i] += red[t + 128][i];
    }
    __syncthreads();
    if (t < 64) {
        #pragma unroll
        for (int i = 0; i < 4; ++i) red[t][i] += red[t + 64][i];
    }
    __syncthreads();
    if (t < 32) {
        #pragma unroll
        for (int i = 0; i < 4; ++i) red[t][i] += red[t + 32][i];
        const size_t poff = ((role == 0) ? PA_OFF : ((role == 1) ? PCI_OFF
                                                                 : PCJ_OFF))
                          + ((size_t)chunk * BB + b) * DD;
        float* P = ws + poff;
        #pragma unroll
        for (int i = 0; i < 4; ++i) P[t * 4 + i] = red[t][i];
    }
}

// ---------------------------------------------------------------------------
// Kernel 2 (v2): u[b][r] = sum_c relu(dm[b]·W1[:,r*128+c] + b1) * w2a[c]
// Redesigned to be VALU-bound instead of LDS-bound:
//   - 8b x 8q register tile (64 acc) per thread
//   - dm staged TRANSPOSED dmsT[k][bb] -> a-frag = 2x ds_read_b128 (broadcast)
//   - W1 streamed global->register, depth-3 rotating prefetch (static idx)
// grid = (64 q-superblocks of 256, 4 b-groups of 64), block = 256.
//   tx = t&31 : q = qbase + tx*8 + j   (r = qbase/128 + (tx>>4), c = (tx&15)*8+j)
//   ty = t>>5 : b = b0 + ty*8 + i
// ---------------------------------------------------------------------------
__global__ __launch_bounds__(256) void k2_gemm(
    const float* __restrict__ d, const float* __restrict__ W1,
    const float* __restrict__ b1, const float* __restrict__ W2,
    float* __restrict__ ws)
{
    const int qbase = blockIdx.x * 256;   // 0..16128
    const int b0    = blockIdx.y * 64;    // 0..192
    const int t   = threadIdx.x;
    const int tx  = t & 31;
    const int ty  = t >> 5;               // 0..7
    const int bb0 = ty * 8;

    // [k][bb]; stride 68: 68*4=272B keeps 16B alignment for bb0 multiples of 4
    __shared__ float dmsT[128][68];

    // stage d[b0+bb][0][k] transposed; global reads coalesced float4 on k
    for (int idx = t; idx < 64 * 32; idx += 256) {
        const int bb = idx >> 5;
        const int k4 = (idx & 31) * 4;
        const float4 v = *(const float4*)(d + (size_t)(b0 + bb) * (NN * DD) + k4);
        dmsT[k4 + 0][bb] = v.x;
        dmsT[k4 + 1][bb] = v.y;
        dmsT[k4 + 2][bb] = v.z;
        dmsT[k4 + 3][bb] = v.w;
    }
    __syncthreads();

    const float* w1p = W1 + qbase + (size_t)tx * 8;  // advance k*16384 per k

    // depth-3 rotating prefetch buffer; all indices compile-time via unroll 4
    float4 wb[4][2];
    #pragma unroll
    for (int pk = 0; pk < 3; ++pk) {
        wb[pk][0] = *(const float4*)(w1p + (size_t)pk * 16384);
        wb[pk][1] = *(const float4*)(w1p + (size_t)pk * 16384 + 4);
    }

    float acc[8][8];
    #pragma unroll
    for (int i = 0; i < 8; ++i) {
        #pragma unroll
        for (int j = 0; j < 8; ++j) acc[i][j] = 0.f;
    }

    #pragma unroll 4
    for (int k = 0; k < 128; ++k) {
        const int kp = (k + 3 < 128) ? (k + 3) : 127;   // clamped (dup) prefetch
        wb[(k + 3) & 3][0] = *(const float4*)(w1p + (size_t)kp * 16384);
        wb[(k + 3) & 3][1] = *(const float4*)(w1p + (size_t)kp * 16384 + 4);

        const float4 alo = *(const float4*)&dmsT[k][bb0];
        const float4 ahi = *(const float4*)&dmsT[k][bb0 + 4];
        const float a[8] = {alo.x, alo.y, alo.z, alo.w,
                            ahi.x, ahi.y, ahi.z, ahi.w};
        const float4 w0 = wb[k & 3][0];
        const float4 w1v = wb[k & 3][1];
        const float wq[8] = {w0.x, w0.y, w0.z, w0.w,
                             w1v.x, w1v.y, w1v.z, w1v.w};
        #pragma unroll
        for (int i = 0; i < 8; ++i) {
            #pragma unroll
            for (int j = 0; j < 8; ++j)
                acc[i][j] = fmaf(a[i], wq[j], acc[i][j]);
        }
    }

    // epilogue: bias + relu + contract over this thread's 8 q's
    const float4 bl = *(const float4*)(b1 + qbase + tx * 8);
    const float4 bh = *(const float4*)(b1 + qbase + tx * 8 + 4);
    const float bias[8] = {bl.x, bl.y, bl.z, bl.w, bh.x, bh.y, bh.z, bh.w};
    const int c0 = (tx & 15) * 8;
    const float4 wal = *(const float4*)(W2 + c0);
    const float4 wah = *(const float4*)(W2 + c0 + 4);
    const float4 wbl = *(const float4*)(W2 + 128 + c0);
    const float4 wbh = *(const float4*)(W2 + 128 + c0 + 4);
    const float wa[8] = {wal.x, wal.y, wal.z, wal.w, wah.x, wah.y, wah.z, wah.w};
    const float wv[8] = {wbl.x, wbl.y, wbl.z, wbl.w, wbh.x, wbh.y, wbh.z, wbh.w};

    float ua[8], va[8];
    #pragma unroll
    for (int i = 0; i < 8; ++i) { ua[i] = 0.f; va[i] = 0.f; }
    #pragma unroll
    for (int j = 0; j < 8; ++j) {
        #pragma unroll
        for (int i = 0; i < 8; ++i) {
            const float g = fmaxf(acc[i][j] + bias[j], 0.f);
            ua[i] = fmaf(g, wa[j], ua[i]);
            va[i] = fmaf(g, wv[j], va[i]);
        }
    }

    // reduce across the 16 c-lanes (width-16 groups align with tx&15)
    #pragma unroll
    for (int off = 8; off > 0; off >>= 1) {
        #pragma unroll
        for (int i = 0; i < 8; ++i) {
            ua[i] += __shfl_down(ua[i], off, 16);
            va[i] += __shfl_down(va[i], off, 16);
        }
    }
    if ((tx & 15) == 0) {
        const int r = (qbase >> 7) + (tx >> 4);   // output row of M
        #pragma unroll
        for (int i = 0; i < 8; ++i) {
            ws[U_OFF + (size_t)(b0 + bb0 + i) * DD + r] = ua[i];
            ws[V_OFF + (size_t)(b0 + bb0 + i) * DD + r] = va[i];
        }
    }
}

// ---------------------------------------------------------------------------
// Kernel 3: per-batch score assembly + sigmoid.
//   out[b] = sigmoid( Adiff·u + (Ci-Cj)·v + b2*cntdiff )
// grid = 256, block = 64 (one wave per batch).
// ---------------------------------------------------------------------------
__global__ __launch_bounds__(64) void k3_final(
    const float* __restrict__ ws, const float* __restrict__ b2p,
    float* __restrict__ out)
{
    const int b = blockIdx.x;
    const int l = threadIdx.x;

    float s = 0.f;
    #pragma unroll
    for (int rep = 0; rep < 2; ++rep) {
        const int k = l + rep * 64;
        float A = 0.f, Ci = 0.f, Cj = 0.f;
        #pragma unroll
        for (int c = 0; c < NCHUNK; ++c) {
            A  += ws[PA_OFF  + ((size_t)c * BB + b) * DD + k];
            Ci += ws[PCI_OFF + ((size_t)c * BB + b) * DD + k];
            Cj += ws[PCJ_OFF + ((size_t)c * BB + b) * DD + k];
        }
        s += A * ws[U_OFF + (size_t)b * DD + k]
           + (Ci - Cj) * ws[V_OFF + (size_t)b * DD + k];
    }
    #pragma unroll
    for (int off = 32; off > 0; off >>= 1) s += __shfl_down(s, off, 64);

    if (l == 0) {
        float cnt = 0.f;
        #pragma unroll
        for (int c = 0; c < NCHUNK; ++c) cnt += ws[PCNT_OFF + c * BB + b];
        const float score = s + b2p[0] * cnt;   // SCALING_FACTOR == 1.0
        out[b] = 1.f / (1.f + expf(-score));
    }
}

extern "C" void kernel_launch(void* const* d_in, const int* in_sizes, int n_in,
                              void* d_out, int out_size, void* d_ws, size_t ws_size,
                              hipStream_t stream)
{
    const float* d   = (const float*)d_in[0];
    const float* si  = (const float*)d_in[1];
    const float* sj  = (const float*)d_in[2];
    const void*  mi  = d_in[3];
    const void*  mj  = d_in[4];
    const float* W1  = (const float*)d_in[5];
    const float* b1  = (const float*)d_in[6];
    const float* W2  = (const float*)d_in[7];
    const float* b2  = (const float*)d_in[8];
    float* ws  = (float*)d_ws;
    float* out = (float*)d_out;

    dim3 g1(NCHUNK, BB, 3);
    k1_sparse<<<g1, 256, 0, stream>>>(d, si, sj, mi, mj, ws);
    dim3 g2(64, 4);
    k2_gemm<<<g2, 256, 0, stream>>>(d, W1, b1, W2, ws);
    k3_final<<<BB, 64, 0, stream>>>(ws, b2, out);
}